// Round 2
// baseline (206.407 us; speedup 1.0000x reference)
//
#include <hip/hip_runtime.h>
#include <hip/hip_bf16.h>

#define LRELU(val) ((val) >= 0.0f ? (val) : 0.01f * (val))

__device__ __forceinline__ float dot4(float4 a, float4 b, float acc) {
    return fmaf(a.x, b.x, fmaf(a.y, b.y, fmaf(a.z, b.z, fmaf(a.w, b.w, acc))));
}

__device__ __forceinline__ float wdot4(const float* __restrict__ wbase, int c, int q,
                                       float4 a, float acc) {
    acc = fmaf(a.x, wbase[(4 * q + 0) * 32 + c], acc);
    acc = fmaf(a.y, wbase[(4 * q + 1) * 32 + c], acc);
    acc = fmaf(a.z, wbase[(4 * q + 2) * 32 + c], acc);
    acc = fmaf(a.w, wbase[(4 * q + 3) * 32 + c], acc);
    return acc;
}

__device__ inline int lower_bound_i(const int* __restrict__ a, int n, int v) {
    int lo = 0, hi = n;
    while (lo < hi) {
        int m = (lo + hi) >> 1;
        if (a[m] < v) lo = m + 1; else hi = m;
    }
    return lo;
}

// Sortable 32-bit distance key from the QUAD-MAJOR transposed array:
// srcT4[q*Ns + j] = float4 of dims 4q..4q+3 of node j. Lane L reads node
// j = start+L+64s -> consecutive lanes, 16B stride. dot accumulation =
// validated dot4 order.
__device__ __forceinline__ unsigned slot_key_T4(
    int s, int lane, int start, int len, int Ns,
    const float4* __restrict__ srcT4, const float* __restrict__ srcn, float ni,
    float4 x0, float4 x1, float4 x2, float4 x3,
    float4 x4, float4 x5, float4 x6, float4 x7)
{
    const int o = lane + 64 * s;
    const bool valid = o < len;
    const int j = valid ? (start + o) : min(start, Ns - 1);
    float dot = 0.0f;
    dot = dot4(srcT4[0 * Ns + j], x0, dot);
    dot = dot4(srcT4[1 * Ns + j], x1, dot);
    dot = dot4(srcT4[2 * Ns + j], x2, dot);
    dot = dot4(srcT4[3 * Ns + j], x3, dot);
    dot = dot4(srcT4[4 * Ns + j], x4, dot);
    dot = dot4(srcT4[5 * Ns + j], x5, dot);
    dot = dot4(srcT4[6 * Ns + j], x6, dot);
    dot = dot4(srcT4[7 * Ns + j], x7, dot);
    const float d2 = (ni + srcn[j]) - 2.0f * dot;   // reference distance formula
    unsigned u = __float_as_uint(d2);
    u = (d2 < 0.0f) ? ~u : (u | 0x80000000u);       // monotone float->uint map
    return valid ? u : 0xFFFFFFFFu;
}

// Membership + compaction for one node (exact lax.top_k tie semantics).
// UNCHANGED (validated): T = 16th-smallest key; ties broken by slot-major,
// lane-minor order = ascending candidate index.
template <int NSL>
__device__ __forceinline__ void select_compact(
    unsigned k0, unsigned k1, unsigned k2, unsigned k3, unsigned k4, unsigned k5,
    unsigned T, int start, int Ns, int* __restrict__ widxW, int lane)
{
    const unsigned long long below = (1ull << lane) - 1ull;
    int m = __popcll(__ballot(k0 < T));
    if (NSL > 1) m += __popcll(__ballot(k1 < T));
    if (NSL > 2) m += __popcll(__ballot(k2 < T));
    if (NSL > 3) m += __popcll(__ballot(k3 < T));
    if (NSL > 4) m += __popcll(__ballot(k4 < T));
    if (NSL > 5) m += __popcll(__ballot(k5 < T));
    const int need = 16 - m;
    const unsigned long long e0 = __ballot(k0 == T);
    const unsigned long long e1 = (NSL > 1) ? __ballot(k1 == T) : 0ull;
    const unsigned long long e2 = (NSL > 2) ? __ballot(k2 == T) : 0ull;
    const unsigned long long e3 = (NSL > 3) ? __ballot(k3 == T) : 0ull;
    const unsigned long long e4 = (NSL > 4) ? __ballot(k4 == T) : 0ull;
    const int eq0 = __popcll(e0), eq1 = eq0 + __popcll(e1), eq2 = eq1 + __popcll(e2),
              eq3 = eq2 + __popcll(e3), eq4 = eq3 + __popcll(e4);
    const bool sel0 = (k0 < T) || ((k0 == T) && (__popcll(e0 & below) < need));
    const bool sel1 = (NSL > 1) && ((k1 < T) || ((k1 == T) && (eq0 + __popcll(e1 & below) < need)));
    const bool sel2 = (NSL > 2) && ((k2 < T) || ((k2 == T) && (eq1 + __popcll(e2 & below) < need)));
    const bool sel3 = (NSL > 3) && ((k3 < T) || ((k3 == T) && (eq2 + __popcll(e3 & below) < need)));
    const bool sel4 = (NSL > 4) && ((k4 < T) || ((k4 == T) && (eq3 + __popcll(e4 & below) < need)));
    const bool sel5 = (NSL > 5) && ((k5 < T) || ((k5 == T) && (eq4 + __popcll(__ballot(k5 == T) & below) < need)));
    const unsigned long long s0 = __ballot(sel0);
    const unsigned long long s1 = __ballot(sel1);
    const unsigned long long s2 = __ballot(sel2);
    const unsigned long long s3 = __ballot(sel3);
    const unsigned long long s4 = __ballot(sel4);
    const unsigned long long s5 = __ballot(sel5);
    const int c0 = __popcll(s0), c1 = c0 + __popcll(s1), c2 = c1 + __popcll(s2),
              c3 = c2 + __popcll(s3), c4 = c3 + __popcll(s4);
    if (lane < 16) widxW[lane] = min(start, Ns - 1);   // fallback, len<16 never in practice
    __builtin_amdgcn_wave_barrier();
    if (sel0) widxW[__popcll(s0 & below)] = start + lane;
    if (NSL > 1 && sel1) widxW[c0 + __popcll(s1 & below)] = start + lane + 64;
    if (NSL > 2 && sel2) widxW[c1 + __popcll(s2 & below)] = start + lane + 128;
    if (NSL > 3 && sel3) widxW[c2 + __popcll(s3 & below)] = start + lane + 192;
    if (NSL > 4 && sel4) widxW[c3 + __popcll(s4 & below)] = start + lane + 256;
    if (NSL > 5 && sel5) widxW[c4 + __popcll(s5 & below)] = start + lane + 320;
    __builtin_amdgcn_wave_barrier();
}

// ---------------------------------------------------------------------------
// ONE node per wave. Distances from the quad-major transposed array
// (coalesced vector loads); neighbor rows from the row-major array.
// 4-ARY ballot bisection: 3 monotone thresholds/iter -> <=16 iterations
// (was 31 binary). Invariant each iter: count(<=hi) >= 16 and
// count(<=lo-1) < 16, so exit lo == T = 16th smallest key, identical to the
// binary version. Bounded for-loop (defensive: non-convergence -> wrong
// answer caught by checker, never a hang). Exact tie-order compaction
// unchanged. No block barriers.
// ---------------------------------------------------------------------------
template <int NSL>
__device__ __forceinline__ void conv_single(
    float4 x0, float4 x1, float4 x2, float4 x3,
    float4 x4, float4 x5, float4 x6, float4 x7,
    float ni, int start, int len,
    const float* __restrict__ srcf, const float4* __restrict__ srcT4,
    const float* __restrict__ srcn, int Ns,
    const float* __restrict__ W, const float* __restrict__ Bc,
    float4 w20, float4 w21, float4 w22, float4 w23,
    float4 w24, float4 w25, float4 w26, float4 w27,
    float4* __restrict__ sNbr, int* __restrict__ widxW,
    int lane, float& vOut)
{
    unsigned k0 = 0xFFFFFFFFu, k1 = 0xFFFFFFFFu, k2 = 0xFFFFFFFFu,
             k3 = 0xFFFFFFFFu, k4 = 0xFFFFFFFFu, k5 = 0xFFFFFFFFu;
    k0 = slot_key_T4(0, lane, start, len, Ns, srcT4, srcn, ni, x0, x1, x2, x3, x4, x5, x6, x7);
    if (NSL > 1 && len > 64)  k1 = slot_key_T4(1, lane, start, len, Ns, srcT4, srcn, ni, x0, x1, x2, x3, x4, x5, x6, x7);
    if (NSL > 2 && len > 128) k2 = slot_key_T4(2, lane, start, len, Ns, srcT4, srcn, ni, x0, x1, x2, x3, x4, x5, x6, x7);
    if (NSL > 3 && len > 192) k3 = slot_key_T4(3, lane, start, len, Ns, srcT4, srcn, ni, x0, x1, x2, x3, x4, x5, x6, x7);
    if (NSL > 4 && len > 256) k4 = slot_key_T4(4, lane, start, len, Ns, srcT4, srcn, ni, x0, x1, x2, x3, x4, x5, x6, x7);
    if (NSL > 5 && len > 320) k5 = slot_key_T4(5, lane, start, len, Ns, srcT4, srcn, ni, x0, x1, x2, x3, x4, x5, x6, x7);

    // 4-ary bisection over the key value space. All valid keys have bit31
    // set, so lo seeds at 0x80000000. Wave-uniform lo/hi (ballot-derived).
    unsigned lo = 0x80000000u, hi = 0xFFFFFFFFu;
#pragma unroll 1
    for (int it = 0; it < 20 && lo < hi; ++it) {
        const unsigned span = hi - lo;
        const unsigned q  = span >> 2;
        const unsigned m1 = lo + q;
        const unsigned m2 = lo + (span >> 1);
        const unsigned m3 = hi - q;
        int c1 = __popcll(__ballot(k0 <= m1));
        int c2 = __popcll(__ballot(k0 <= m2));
        int c3 = __popcll(__ballot(k0 <= m3));
        if (NSL > 1) { c1 += __popcll(__ballot(k1 <= m1)); c2 += __popcll(__ballot(k1 <= m2)); c3 += __popcll(__ballot(k1 <= m3)); }
        if (NSL > 2) { c1 += __popcll(__ballot(k2 <= m1)); c2 += __popcll(__ballot(k2 <= m2)); c3 += __popcll(__ballot(k2 <= m3)); }
        if (NSL > 3) { c1 += __popcll(__ballot(k3 <= m1)); c2 += __popcll(__ballot(k3 <= m2)); c3 += __popcll(__ballot(k3 <= m3)); }
        if (NSL > 4) { c1 += __popcll(__ballot(k4 <= m1)); c2 += __popcll(__ballot(k4 <= m2)); c3 += __popcll(__ballot(k4 <= m3)); }
        if (NSL > 5) { c1 += __popcll(__ballot(k5 <= m1)); c2 += __popcll(__ballot(k5 <= m2)); c3 += __popcll(__ballot(k5 <= m3)); }
        if (c1 >= 16) hi = m1;
        else if (c2 >= 16) { lo = m1 + 1; hi = m2; }
        else if (c3 >= 16) { lo = m2 + 1; hi = m3; }
        else lo = m3 + 1;   // count(<=hi)>=16 invariant => interval stays valid
    }

    select_compact<NSL>(k0, k1, k2, k3, k4, k5, lo, start, Ns, widxW, lane);

    const int c = lane & 31;
    const int n0 = lane >> 3, qq = lane & 7;
    const int n1 = n0 + 8;
    int j0 = widxW[n0]; j0 = ((unsigned)j0 < (unsigned)Ns) ? j0 : 0;
    int j1 = widxW[n1]; j1 = ((unsigned)j1 < (unsigned)Ns) ? j1 : 0;
    const float4* S = reinterpret_cast<const float4*>(srcf);
    const float4 r0 = S[(size_t)j0 * 8 + qq];
    const float4 r1 = S[(size_t)j1 * 8 + qq];

    float base = Bc[c];
    base = wdot4(W, c, 0, x0, base); base = wdot4(W, c, 1, x1, base);
    base = wdot4(W, c, 2, x2, base); base = wdot4(W, c, 3, x3, base);
    base = wdot4(W, c, 4, x4, base); base = wdot4(W, c, 5, x5, base);
    base = wdot4(W, c, 6, x6, base); base = wdot4(W, c, 7, x7, base);
    float dd = 0.0f;
    dd = dot4(x0, w20, dd); dd = dot4(x1, w21, dd); dd = dot4(x2, w22, dd); dd = dot4(x3, w23, dd);
    dd = dot4(x4, w24, dd); dd = dot4(x5, w25, dd); dd = dot4(x6, w26, dd); dd = dot4(x7, w27, dd);
    const float cbase = base - dd;

    sNbr[n0 * 8 + qq] = r0;
    sNbr[n1 * 8 + qq] = r1;
    __builtin_amdgcn_wave_barrier();

    const int half = lane >> 5;
    float vm = -__builtin_huge_valf();
#pragma unroll 1
    for (int r = 0; r < 8; ++r) {
        const float4* nb = sNbr + (2 * r + half) * 8;
        float acc = cbase;
        acc = dot4(nb[0], w20, acc);
        acc = dot4(nb[1], w21, acc);
        acc = dot4(nb[2], w22, acc);
        acc = dot4(nb[3], w23, acc);
        acc = dot4(nb[4], w24, acc);
        acc = dot4(nb[5], w25, acc);
        acc = dot4(nb[6], w26, acc);
        acc = dot4(nb[7], w27, acc);
        vm = fmaxf(vm, LRELU(acc));
    }
    vm = fmaxf(vm, __shfl_xor(vm, 32));
    vOut = vm;
}

// ---------------------------------------------------------------------------
// Kernel 1: both MLP2 encoders + sq norms + group-offset tables + quad-major
// transposed feature copies (encT4[q*Nn + node] = float4 of dims 4q..4q+3).
// ---------------------------------------------------------------------------
__launch_bounds__(256)
__global__ void encode_kernel(const float* __restrict__ x_pfc, const float* __restrict__ x_vtx,
                              const int* __restrict__ bpfc, const int* __restrict__ bvtx,
                              const float* __restrict__ pw1, const float* __restrict__ pb1,
                              const float* __restrict__ pw2, const float* __restrict__ pb2,
                              const float* __restrict__ vw1, const float* __restrict__ vb1,
                              const float* __restrict__ vw2, const float* __restrict__ vb2,
                              float* __restrict__ pfc_enc, float* __restrict__ pfc_norm,
                              float* __restrict__ vtx_enc, float* __restrict__ vtx_norm,
                              float* __restrict__ pfc_encT4, float* __restrict__ vtx_encT4,
                              int* __restrict__ goff_pfc, int* __restrict__ goff_vtx) {
    __shared__ float h1s[8][32];
    const int t = threadIdx.x;
    const int c = t & 31;
    const int nl = t >> 5;

    if (blockIdx.x == 0) {
        if (t < 33) goff_pfc[t] = lower_bound_i(bpfc, 8192, t);
        else if (t >= 64 && t < 97) goff_vtx[t - 64] = lower_bound_i(bvtx, 2048, t - 64);
    }

    const bool is_pfc = (blockIdx.x < 1024);
    const int node = (is_pfc ? blockIdx.x : (blockIdx.x - 1024)) * 8 + nl;
    const int din = is_pfc ? 7 : 4;
    const int Nn = is_pfc ? 8192 : 2048;
    const float* __restrict__ xin = is_pfc ? (x_pfc + node * 7) : (x_vtx + node * 4);
    const float* __restrict__ w1 = is_pfc ? pw1 : vw1;
    const float* __restrict__ b1 = is_pfc ? pb1 : vb1;
    const float* __restrict__ w2 = is_pfc ? pw2 : vw2;
    const float* __restrict__ b2 = is_pfc ? pb2 : vb2;
    float* __restrict__ enc   = is_pfc ? pfc_enc : vtx_enc;
    float* __restrict__ encT4 = is_pfc ? pfc_encT4 : vtx_encT4;
    float* __restrict__ nrm   = is_pfc ? pfc_norm : vtx_norm;

    float h1 = b1[c];
    for (int d = 0; d < din; ++d) h1 = fmaf(xin[d], w1[d * 32 + c], h1);
    h1 = LRELU(h1);
    h1s[nl][c] = h1;
    __syncthreads();

    float h2 = b2[c];
#pragma unroll
    for (int d = 0; d < 32; ++d) h2 = fmaf(h1s[nl][d], w2[d * 32 + c], h2);
    h2 = LRELU(h2);
    enc[node * 32 + c] = h2;
    // quad-major transpose: dim c -> quad c>>2, elem c&3
    encT4[((size_t)(c >> 2) * Nn + node) * 4 + (c & 3)] = h2;

    float s = h2 * h2;
#pragma unroll
    for (int m = 16; m >= 1; m >>= 1) s += __shfl_xor(s, m);
    if (c == 0) nrm[node] = s;
}

// ---------------------------------------------------------------------------
// Kernel 2: fused conv1 + conv2 + output MLP. ONE node per 64-thread block
// (one wave): 8192 independently-retiring waves for finest drain
// granularity (tail was the occupancy killer: 18.8% avg vs 50% static
// ceiling). LDS ~2.5KB/block; __launch_bounds__(64,4) caps VGPR at 128 ->
// 16 waves/CU resident. Zero block barriers.
// ---------------------------------------------------------------------------
__launch_bounds__(64, 4)
__global__ void fused_conv_mlp_kernel(
    const float* __restrict__ pfc_enc, const float4* __restrict__ pfc_encT4,
    const float* __restrict__ n_pfc,
    const float* __restrict__ vtx_enc, const float4* __restrict__ vtx_encT4,
    const float* __restrict__ n_vtx,
    const int* __restrict__ bpfc,
    const int* __restrict__ goff_pfc, const int* __restrict__ goff_vtx,
    const float* __restrict__ W, const float* __restrict__ Bc,
    const float* __restrict__ ow1, const float* __restrict__ ob1,
    const float* __restrict__ ow2, const float* __restrict__ ob2,
    const float* __restrict__ ow3, const float* __restrict__ ob3,
    const float* __restrict__ ow4, const float* __restrict__ ob4,
    float* __restrict__ dout, int N)
{
    __shared__ __align__(16) float4 sNbr[128];
    __shared__ int widx[16];
    __shared__ __align__(16) float sRow[32];
    __shared__ float sEx1[64];

    const int lane = threadIdx.x & 63;
    const int b = blockIdx.x;              // 8192 blocks x 1 node
    const int xcd = b & 7, chunk = b >> 3;
    const int i = xcd * 1024 + chunk;      // XCD-contiguous node slices for L2
    const int c = lane & 31;

    // W2 column (rows 32..63, col c) into 8 float4 regs (L2-hot broadcast)
    const float4 w20 = make_float4(W[32 * 32 + c], W[33 * 32 + c], W[34 * 32 + c], W[35 * 32 + c]);
    const float4 w21 = make_float4(W[36 * 32 + c], W[37 * 32 + c], W[38 * 32 + c], W[39 * 32 + c]);
    const float4 w22 = make_float4(W[40 * 32 + c], W[41 * 32 + c], W[42 * 32 + c], W[43 * 32 + c]);
    const float4 w23 = make_float4(W[44 * 32 + c], W[45 * 32 + c], W[46 * 32 + c], W[47 * 32 + c]);
    const float4 w24 = make_float4(W[48 * 32 + c], W[49 * 32 + c], W[50 * 32 + c], W[51 * 32 + c]);
    const float4 w25 = make_float4(W[52 * 32 + c], W[53 * 32 + c], W[54 * 32 + c], W[55 * 32 + c]);
    const float4 w26 = make_float4(W[56 * 32 + c], W[57 * 32 + c], W[58 * 32 + c], W[59 * 32 + c]);
    const float4 w27 = make_float4(W[60 * 32 + c], W[61 * 32 + c], W[62 * 32 + c], W[63 * 32 + c]);

    const int g = bpfc[i];

    // ---- conv1: src = dst = pfc ----
    const float4* x = reinterpret_cast<const float4*>(pfc_enc + (size_t)i * 32);
    const float4 a0 = x[0], a1 = x[1], a2 = x[2], a3 = x[3],
                 a4 = x[4], a5 = x[5], a6 = x[6], a7 = x[7];
    const float ni = n_pfc[i];
    const int s1 = goff_pfc[g], len1 = min(goff_pfc[g + 1] - s1, 384);

    float v1;
    if (((len1 + 63) >> 6) <= 4)
        conv_single<4>(a0, a1, a2, a3, a4, a5, a6, a7, ni, s1, len1,
                       pfc_enc, pfc_encT4, n_pfc, 8192, W, Bc,
                       w20, w21, w22, w23, w24, w25, w26, w27,
                       sNbr, widx, lane, v1);
    else
        conv_single<6>(a0, a1, a2, a3, a4, a5, a6, a7, ni, s1, len1,
                       pfc_enc, pfc_encT4, n_pfc, 8192, W, Bc,
                       w20, w21, w22, w23, w24, w25, w26, w27,
                       sNbr, widx, lane, v1);

    if (lane < 32) sRow[lane] = v1;
    float nf = v1 * v1;
#pragma unroll
    for (int m = 16; m >= 1; m >>= 1) nf += __shfl_xor(nf, m);
    __builtin_amdgcn_wave_barrier();

    // ---- conv2: dst = feats1 row (wave-private LDS), src = vtx ----
    const float4* f = reinterpret_cast<const float4*>(&sRow[0]);
    const float4 y0 = f[0], y1 = f[1], y2 = f[2], y3 = f[3],
                 y4 = f[4], y5 = f[5], y6 = f[6], y7 = f[7];
    const int s2 = goff_vtx[g], len2 = min(goff_vtx[g + 1] - s2, 128);

    float v2;
    conv_single<2>(y0, y1, y2, y3, y4, y5, y6, y7, nf, s2, len2,
                   vtx_enc, vtx_encT4, n_vtx, 2048, W, Bc,
                   w20, w21, w22, w23, w24, w25, w26, w27,
                   sNbr, widx, lane, v2);

    // ---- output MLP 32 -> 64 -> 32 -> 4 -> 1 (lrelu each), wave-private ----
    if (lane < 32) sRow[lane] = v2;
    __builtin_amdgcn_wave_barrier();

    // layer 1: 64 outputs, one per lane (weights from global, L2-hot)
    {
        float h1 = ob1[lane];
#pragma unroll
        for (int d = 0; d < 32; ++d) h1 = fmaf(sRow[d], ow1[d * 64 + lane], h1);
        sEx1[lane] = LRELU(h1);
    }
    __builtin_amdgcn_wave_barrier();

    // layer 2: 32 outputs (both halves duplicate)
    {
        float h2 = ob2[c];
#pragma unroll
        for (int d = 0; d < 64; ++d) h2 = fmaf(sEx1[d], ow2[d * 32 + c], h2);
        if (lane < 32) sRow[lane] = LRELU(h2);
    }
    __builtin_amdgcn_wave_barrier();

    // layers 3+4 (tiny): wave-uniform weight reads -> scalar loads
    {
        float a0_ = ob3[0], a1_ = ob3[1], a2_ = ob3[2], a3_ = ob3[3];
#pragma unroll
        for (int d = 0; d < 32; ++d) {
            const float e = sRow[d];
            a0_ = fmaf(e, ow3[d * 4 + 0], a0_);
            a1_ = fmaf(e, ow3[d * 4 + 1], a1_);
            a2_ = fmaf(e, ow3[d * 4 + 2], a2_);
            a3_ = fmaf(e, ow3[d * 4 + 3], a3_);
        }
        a0_ = LRELU(a0_); a1_ = LRELU(a1_); a2_ = LRELU(a2_); a3_ = LRELU(a3_);
        float o = ob4[0];
        o = fmaf(a0_, ow4[0], o); o = fmaf(a1_, ow4[1], o);
        o = fmaf(a2_, ow4[2], o); o = fmaf(a3_, ow4[3], o);
        o = LRELU(o);

        if (lane == 0) dout[i] = o;                     // output 0
        if (lane == 1) dout[N + i] = (float)g;          // output 1
    }
}

// ---------------------------------------------------------------------------
extern "C" void kernel_launch(void* const* d_in, const int* in_sizes, int n_in,
                              void* d_out, int out_size, void* d_ws, size_t ws_size,
                              hipStream_t stream) {
    const float* x_pfc     = (const float*)d_in[0];
    const float* x_vtx     = (const float*)d_in[1];
    const int*   batch_pfc = (const int*)d_in[2];
    const int*   batch_vtx = (const int*)d_in[3];
    const float* pfc_w1 = (const float*)d_in[4];
    const float* pfc_b1 = (const float*)d_in[5];
    const float* pfc_w2 = (const float*)d_in[6];
    const float* pfc_b2 = (const float*)d_in[7];
    const float* vtx_w1 = (const float*)d_in[8];
    const float* vtx_b1 = (const float*)d_in[9];
    const float* vtx_w2 = (const float*)d_in[10];
    const float* vtx_b2 = (const float*)d_in[11];
    const float* conv_w = (const float*)d_in[12];
    const float* conv_b = (const float*)d_in[13];
    const float* out_w1 = (const float*)d_in[14];
    const float* out_b1 = (const float*)d_in[15];
    const float* out_w2 = (const float*)d_in[16];
    const float* out_b2 = (const float*)d_in[17];
    const float* out_w3 = (const float*)d_in[18];
    const float* out_b3 = (const float*)d_in[19];
    const float* out_w4 = (const float*)d_in[20];
    const float* out_b4 = (const float*)d_in[21];

    const int N_PFC = 8192;

    float* ws = (float*)d_ws;
    float* pfc_enc   = ws;                     // 8192*32
    float* vtx_enc   = ws + 262144;            // 2048*32
    float* n_pfc     = ws + 327680;            // 8192
    float* n_vtx     = ws + 335872;            // 2048
    int*   goff_pfc  = (int*)(ws + 337920);    // 33 (+pad)
    int*   goff_vtx  = (int*)(ws + 337984);    // 33 (+pad)
    float* pfc_encT4 = ws + 338048;            // 8 quads * 8192 * 4 = 262144
    float* vtx_encT4 = ws + 600192;            // 8 * 2048 * 4 = 65536  (total 665728 floats)

    encode_kernel<<<1280, 256, 0, stream>>>(x_pfc, x_vtx, batch_pfc, batch_vtx,
                                            pfc_w1, pfc_b1, pfc_w2, pfc_b2,
                                            vtx_w1, vtx_b1, vtx_w2, vtx_b2,
                                            pfc_enc, n_pfc, vtx_enc, n_vtx,
                                            pfc_encT4, vtx_encT4,
                                            goff_pfc, goff_vtx);

    fused_conv_mlp_kernel<<<8192, 64, 0, stream>>>(
        pfc_enc, (const float4*)pfc_encT4, n_pfc,
        vtx_enc, (const float4*)vtx_encT4, n_vtx,
        batch_pfc, goff_pfc, goff_vtx, conv_w, conv_b,
        out_w1, out_b1, out_w2, out_b2, out_w3, out_b3, out_w4, out_b4,
        (float*)d_out, N_PFC);
}